// Round 7
// baseline (117.890 us; speedup 1.0000x reference)
//
#include <hip/hip_runtime.h>
#include <hip/hip_cooperative_groups.h>

namespace cg = cooperative_groups;

#define NBATCH  4
#define NPTS    4096
#define XPT     8                        // x-points per thread (phase 1)
#define XCHUNK  (256 * XPT)              // 2048
#define NXC     (NPTS / XCHUNK)          // 2
#define YCHUNK  128
#define NYC     (NPTS / YCHUNK)          // 32
#define NBLK    (NXC * NYC * 2 * NBATCH) // 512 blocks
#define NPOINTS (2 * NBATCH * NPTS)      // 32768
#define P2BLK   (NPOINTS / 256)          // 128 blocks active in phase 2
#define BIGF    1e30f

// Single-dispatch fused chamfer loss (cooperative launch, 2 grid syncs).
// Phase 1: 512 blocks compute partial[dir][b][yc][x] = rx + min_chunk(ry - 2 x.y)
// Phase 2: 128 blocks: per-point min over NYC rows, mask dir-1, block sums
// Phase 3: block 0 sums the 128 block sums -> out[0] (plain store, no atomics)
__global__ __launch_bounds__(256)
void chamfer_fused_kernel(const float* __restrict__ preds,
                          const float* __restrict__ gts,
                          const int* __restrict__ mask,
                          float* __restrict__ partial,
                          float* __restrict__ blocksum,
                          float* __restrict__ out) {
    cg::grid_group grid = cg::this_grid();
    const int bid = blockIdx.x;
    const int tid = threadIdx.x;

    // ---------------- Phase 1 ----------------
    {
        const int xc  = bid & (NXC - 1);          // 0..1
        const int yc  = (bid >> 1) & (NYC - 1);   // 0..31
        const int zc  = bid >> 6;                 // 0..7
        const int dir = zc >> 2;
        const int b   = zc & 3;

        const float* X = (dir == 0 ? preds : gts) + (size_t)b * NPTS * 3;
        const float* Y = (dir == 0 ? gts : preds) + (size_t)b * NPTS * 3;

        __shared__ float4 sy[YCHUNK];
        const int cbase = yc * YCHUNK;
        if (tid < YCHUNK) {
            const int j = cbase + tid;
            const float y0 = Y[j * 3 + 0];
            const float y1 = Y[j * 3 + 1];
            const float y2 = Y[j * 3 + 2];
            float ry = y0 * y0 + y1 * y1 + y2 * y2;
            if (dir == 0 && mask[b * NPTS + j] == 0) ry = BIGF;
            sy[tid] = make_float4(y0, y1, y2, ry);
        }
        __syncthreads();

        float a0[XPT], a1[XPT], a2[XPT], rx[XPT], m[XPT];
        const int xbase = xc * XCHUNK + tid;
        #pragma unroll
        for (int i = 0; i < XPT; ++i) {
            const int x = xbase + i * 256;
            float v0 = X[x * 3 + 0], v1 = X[x * 3 + 1], v2 = X[x * 3 + 2];
            rx[i] = v0 * v0 + v1 * v1 + v2 * v2;
            a0[i] = -2.0f * v0; a1[i] = -2.0f * v1; a2[i] = -2.0f * v2;
            m[i] = BIGF;
        }

        #pragma unroll 2
        for (int k = 0; k < YCHUNK; k += 4) {
            const float4 p0 = sy[k + 0];
            const float4 p1 = sy[k + 1];
            const float4 p2 = sy[k + 2];
            const float4 p3 = sy[k + 3];
            #pragma unroll
            for (int i = 0; i < XPT; ++i) {
                const float t0 = fmaf(a0[i], p0.x, fmaf(a1[i], p0.y, fmaf(a2[i], p0.z, p0.w)));
                const float t1 = fmaf(a0[i], p1.x, fmaf(a1[i], p1.y, fmaf(a2[i], p1.z, p1.w)));
                const float t2 = fmaf(a0[i], p2.x, fmaf(a1[i], p2.y, fmaf(a2[i], p2.z, p2.w)));
                const float t3 = fmaf(a0[i], p3.x, fmaf(a1[i], p3.y, fmaf(a2[i], p3.z, p3.w)));
                m[i] = fminf(fminf(m[i], t0), t1);   // -> v_min3_f32
                m[i] = fminf(fminf(m[i], t2), t3);   // -> v_min3_f32
            }
        }

        float* prow = partial + ((size_t)zc * NYC + yc) * NPTS + xc * XCHUNK + tid;
        #pragma unroll
        for (int i = 0; i < XPT; ++i)
            prow[i * 256] = rx[i] + m[i];
    }

    grid.sync();

    // ---------------- Phase 2 ----------------
    if (bid < P2BLK) {
        const int p   = bid * 256 + tid;    // point id
        const int dir = p >> 14;
        const int b   = (p >> 12) & 3;
        const int x   = p & 4095;

        const float* basep = partial + ((size_t)(dir * NBATCH + b) * NYC) * NPTS + x;
        float m = basep[0];
        #pragma unroll
        for (int c = 1; c < NYC; ++c) m = fminf(m, basep[(size_t)c * NPTS]);

        float v = m;
        if (dir == 1 && mask[b * NPTS + x] == 0) v = 0.0f;

        #pragma unroll
        for (int off = 32; off > 0; off >>= 1)
            v += __shfl_down(v, off, 64);

        __shared__ float wsum[4];
        if ((tid & 63) == 0) wsum[tid >> 6] = v;
        __syncthreads();
        if (tid == 0)
            blocksum[bid] = wsum[0] + wsum[1] + wsum[2] + wsum[3];
    }

    grid.sync();

    // ---------------- Phase 3 ----------------
    if (bid == 0) {
        float v = (tid < P2BLK) ? blocksum[tid] : 0.0f;
        #pragma unroll
        for (int off = 32; off > 0; off >>= 1)
            v += __shfl_down(v, off, 64);

        __shared__ float fsum[4];
        if ((tid & 63) == 0) fsum[tid >> 6] = v;
        __syncthreads();
        if (tid == 0)
            out[0] = fsum[0] + fsum[1] + fsum[2] + fsum[3];
    }
}

extern "C" void kernel_launch(void* const* d_in, const int* in_sizes, int n_in,
                              void* d_out, int out_size, void* d_ws, size_t ws_size,
                              hipStream_t stream) {
    const float* preds = (const float*)d_in[0];  // [B, Npred, 3]
    const float* gts   = (const float*)d_in[1];  // [B, Ngt, 3]
    const int*   mask  = (const int*)d_in[2];    // [B, Ngt]
    float* out = (float*)d_out;

    float* partial  = (float*)d_ws;                              // [8][NYC][NPTS] = 4 MB
    float* blocksum = partial + (size_t)8 * NYC * NPTS;          // [128]

    void* args[] = {(void*)&preds, (void*)&gts, (void*)&mask,
                    (void*)&partial, (void*)&blocksum, (void*)&out};
    hipLaunchCooperativeKernel((void*)chamfer_fused_kernel,
                               dim3(NBLK), dim3(256), args, 0, stream);
}

// Round 12
// 28.954 us; speedup vs baseline: 4.0716x; 4.0716x over previous
//
#include <hip/hip_runtime.h>

#define NBATCH 4
#define NPTS   4096
#define XCB    64                 // x-points per block
#define NXB    (NPTS / XCB)       // 64 x-chunks per (dir,b)
#define NBLK   (2 * NBATCH * NXB) // 512 blocks
#define YSPLIT 4                  // waves per block split the y range
#define YLEN   (NPTS / YSPLIT)    // 1024
#define BIGF   1e30f

// Single-dispatch chamfer loss. Each block: 64 x-points vs ALL 4096 y-points
// (y staged in 64KB LDS; each of the 4 waves scans a quarter, combine in LDS).
// Cross-block: release flag + block-0 spin-consume (deadlock-free: only block 0
// waits; producers never wait). Flags self-clean to 0; poison 0xAAAAAAAA != 1.
__global__ __launch_bounds__(256, 2)
void chamfer_onepass_kernel(const float* __restrict__ preds,
                            const float* __restrict__ gts,
                            const int* __restrict__ mask,
                            float* __restrict__ blocksum,
                            unsigned* __restrict__ flags,
                            float* __restrict__ out) {
    const int bid = blockIdx.x;
    const int tid = threadIdx.x;
    const int zc  = bid >> 6;        // 0..7 = dir*4 + b
    const int xc  = bid & (NXB - 1); // x-chunk within (dir,b)
    const int dir = zc >> 2;
    const int b   = zc & 3;

    const float* X = (dir == 0 ? preds : gts) + (size_t)b * NPTS * 3;
    const float* Y = (dir == 0 ? gts : preds) + (size_t)b * NPTS * 3;

    // ---- producer: 64 x vs all y ----
    __shared__ float4 sy[NPTS];      // 64 KB
    for (int t = tid; t < NPTS; t += 256) {
        const float y0 = Y[t * 3 + 0];
        const float y1 = Y[t * 3 + 1];
        const float y2 = Y[t * 3 + 2];
        float ry = y0 * y0 + y1 * y1 + y2 * y2;
        if (dir == 0 && mask[b * NPTS + t] == 0) ry = BIGF;
        sy[t] = make_float4(y0, y1, y2, ry);
    }

    const int lx = tid & 63;         // x lane
    const int q  = tid >> 6;         // y-quarter (wave id)
    const int x  = xc * XCB + lx;
    const float v0 = X[x * 3 + 0], v1 = X[x * 3 + 1], v2 = X[x * 3 + 2];
    const float rx = v0 * v0 + v1 * v1 + v2 * v2;
    const float a0 = -2.0f * v0, a1 = -2.0f * v1, a2 = -2.0f * v2;

    __syncthreads();

    float m = BIGF;
    const int kbeg = q * YLEN;
    #pragma unroll 2
    for (int k = kbeg; k < kbeg + YLEN; k += 4) {
        const float4 p0 = sy[k + 0];   // wave-uniform address -> broadcast
        const float4 p1 = sy[k + 1];
        const float4 p2 = sy[k + 2];
        const float4 p3 = sy[k + 3];
        const float t0 = fmaf(a0, p0.x, fmaf(a1, p0.y, fmaf(a2, p0.z, p0.w)));
        const float t1 = fmaf(a0, p1.x, fmaf(a1, p1.y, fmaf(a2, p1.z, p1.w)));
        const float t2 = fmaf(a0, p2.x, fmaf(a1, p2.y, fmaf(a2, p2.z, p2.w)));
        const float t3 = fmaf(a0, p3.x, fmaf(a1, p3.y, fmaf(a2, p3.z, p3.w)));
        m = fminf(fminf(m, t0), t1);   // -> v_min3_f32
        m = fminf(fminf(m, t2), t3);   // -> v_min3_f32
    }

    // combine the 4 y-quarters per x, then block sum (wave 0 only)
    __shared__ float sm[YSPLIT][XCB];
    sm[q][lx] = m;
    __syncthreads();

    if (q == 0) {
        const float mm = fminf(fminf(sm[0][lx], sm[1][lx]),
                               fminf(sm[2][lx], sm[3][lx]));
        float val = rx + mm;
        if (dir == 1 && mask[b * NPTS + x] == 0) val = 0.0f;

        #pragma unroll
        for (int off = 32; off > 0; off >>= 1)
            val += __shfl_down(val, off, 64);

        if (lx == 0) {
            __hip_atomic_store(&blocksum[bid], val, __ATOMIC_RELAXED,
                               __HIP_MEMORY_SCOPE_AGENT);
            __hip_atomic_store(&flags[bid], 1u, __ATOMIC_RELEASE,
                               __HIP_MEMORY_SCOPE_AGENT);
        }
    }

    // ---- consumer: block 0 spins (its own flag already set above) ----
    if (bid == 0) {
        float acc = 0.0f;
        #pragma unroll
        for (int r = 0; r < NBLK / 256; ++r) {
            const int i = r * 256 + tid;
            while (__hip_atomic_load(&flags[i], __ATOMIC_ACQUIRE,
                                     __HIP_MEMORY_SCOPE_AGENT) != 1u) {}
            acc += __hip_atomic_load(&blocksum[i], __ATOMIC_RELAXED,
                                     __HIP_MEMORY_SCOPE_AGENT);
            __hip_atomic_store(&flags[i], 0u, __ATOMIC_RELAXED,
                               __HIP_MEMORY_SCOPE_AGENT);
        }
        #pragma unroll
        for (int off = 32; off > 0; off >>= 1)
            acc += __shfl_down(acc, off, 64);

        __shared__ float ws4[4];
        if ((tid & 63) == 0) ws4[tid >> 6] = acc;
        __syncthreads();
        if (tid == 0)
            out[0] = ws4[0] + ws4[1] + ws4[2] + ws4[3];
    }
}

extern "C" void kernel_launch(void* const* d_in, const int* in_sizes, int n_in,
                              void* d_out, int out_size, void* d_ws, size_t ws_size,
                              hipStream_t stream) {
    const float* preds = (const float*)d_in[0];  // [B, Npred, 3]
    const float* gts   = (const float*)d_in[1];  // [B, Ngt, 3]
    const int*   mask  = (const int*)d_in[2];    // [B, Ngt]
    float* out = (float*)d_out;

    float*    blocksum = (float*)d_ws;            // [512]
    unsigned* flags    = (unsigned*)(blocksum + NBLK);  // [512]

    chamfer_onepass_kernel<<<NBLK, 256, 0, stream>>>(
        preds, gts, mask, blocksum, flags, out);
}